// Round 1
// baseline (174.282 us; speedup 1.0000x reference)
//
#include <hip/hip_runtime.h>
#include <hip/hip_bf16.h>
#include <stdint.h>

#define B_ 64
#define T_ 256
#define K_ 48
#define KK 2304               // K_*K_
#define D_PRE 6               // prefetch ring depth (slots); +1 dummy slot
#define START_TAG 46
#define END_TAG 47
// per tile: 9216 B = 9 instrs x 1KB (64 lanes x 16B)
// steady state outstanding = 9*D_PRE = 54 <= 63; wait immediate = 9*(D_PRE-1) = 45

typedef const __attribute__((address_space(1))) void* gas_t;
typedef __attribute__((address_space(3))) void* las_t;

__device__ __forceinline__ void gload_lds_1k(const float* gsrc, float* ldst, int lane) {
    // each lane supplies its own global address; LDS dest is wave-uniform base + lane*16
    __builtin_amdgcn_global_load_lds((gas_t)(gsrc + lane * 4), (las_t)ldst, 16, 0, 0);
}

__device__ __forceinline__ void issue_tile(const float* src, float* slot, int lane) {
#pragma unroll
    for (int k = 0; k < 9; ++k)
        gload_lds_1k(src + k * 256, slot + k * 256, lane);
}

__launch_bounds__(256, 1)
__global__ void crf_fwd_kernel(const float* __restrict__ scores,
                               const int* __restrict__ targets,
                               const int* __restrict__ lengths,
                               float* __restrict__ ws) {
    __shared__ __align__(16) float tiles[(D_PRE + 1) * KK];  // +1 = dummy slot
    __shared__ float prev_s[K_];
    __shared__ float red_s[4];

    const int b    = blockIdx.x;
    const int tid  = threadIdx.x;
    const int lane = tid & 63;
    const int wid  = tid >> 6;

    int len = lengths[b];
    len = min(max(len, 1), T_);
    const int last_t = len - 1;  // tiles 1..last_t participate in the recurrence

    const float* sb = scores + (size_t)b * T_ * KK;

    // ---- gold score: one t per thread (T_ == blockDim) ----
    float g = 0.f;
    {
        const int t0 = tid;
        if (t0 < len) {
            const int tgt = targets[b * T_ + t0];
            g = sb[(size_t)t0 * KK + tgt];
        }
#pragma unroll
        for (int off = 1; off < 64; off <<= 1) g += __shfl_xor(g, off);
        if (lane == 0) red_s[wid] = g;
    }

    // ---- init: prev[j] = scores[b,0,START_TAG,j] ----
    if (tid < K_) prev_s[tid] = sb[START_TAG * K_ + tid];

    __syncthreads();  // drains all vm loads (gold gathers) -> clean vmcnt for producer

    float gold_reg = 0.f;
    if (tid == 0) gold_reg = red_s[0] + red_s[1] + red_s[2] + red_s[3];

    // ---- producer prologue: fill the ring (dummy slot keeps count uniform) ----
    if (wid == 3) {
#pragma unroll
        for (int k = 1; k <= D_PRE; ++k) {
            const bool real = (k <= last_t);
            const float* src = real ? (sb + (size_t)k * KK) : sb;
            float* dst = real ? &tiles[(k % D_PRE) * KK] : &tiles[D_PRE * KK];
            issue_tile(src, dst, lane);
        }
    }

    // ---- main recurrence ----
    for (int t = 1; t <= last_t; ++t) {
        if (wid == 3) asm volatile("s_waitcnt vmcnt(45)" ::: "memory");  // tile t landed
        asm volatile("s_waitcnt lgkmcnt(0)" ::: "memory");               // prev write done
        __builtin_amdgcn_s_barrier();  // A: tile t + prev visible to all

        float lse = 0.f;
        const float* tile = &tiles[(t % D_PRE) * KK];
        if (tid < 192) {
            const int j = tid >> 2, gq = tid & 3;
            float v[12];
            float m = -INFINITY;
#pragma unroll
            for (int it = 0; it < 12; ++it) {
                const int i = gq + (it << 2);          // 2-way LDS aliasing only
                const float x = tile[i * K_ + j] + prev_s[i];
                v[it] = x;
                m = fmaxf(m, x);
            }
            m = fmaxf(m, __shfl_xor(m, 1));
            m = fmaxf(m, __shfl_xor(m, 2));
            float s = 0.f;
#pragma unroll
            for (int it = 0; it < 12; ++it) s += __expf(v[it] - m);
            s += __shfl_xor(s, 1);
            s += __shfl_xor(s, 2);
            lse = m + __logf(s);
        }

        asm volatile("s_waitcnt lgkmcnt(0)" ::: "memory");  // all tile-t reads retired
        __builtin_amdgcn_s_barrier();  // B: safe to overwrite slot / prev

        if (wid == 3) {
            const int tn = t + D_PRE;
            const bool real = (tn <= last_t);
            const float* src = real ? (sb + (size_t)tn * KK) : sb;
            float* dst = real ? &tiles[(tn % D_PRE) * KK] : &tiles[D_PRE * KK];
            issue_tile(src, dst, lane);
        } else if ((tid & 3) == 0) {
            prev_s[tid >> 2] = lse;
        }
    }

    if (wid == 3) asm volatile("s_waitcnt vmcnt(0)" ::: "memory");  // drain dummies
    asm volatile("s_waitcnt lgkmcnt(0)" ::: "memory");
    __builtin_amdgcn_s_barrier();

    if (tid == 0) ws[b] = prev_s[END_TAG] - gold_reg;
}

__global__ void reduce_kernel(const float* __restrict__ ws, float* __restrict__ out) {
    float v = ws[threadIdx.x];
#pragma unroll
    for (int off = 1; off < 64; off <<= 1) v += __shfl_xor(v, off);
    if (threadIdx.x == 0) out[0] = v * (1.0f / 64.0f);
}

extern "C" void kernel_launch(void* const* d_in, const int* in_sizes, int n_in,
                              void* d_out, int out_size, void* d_ws, size_t ws_size,
                              hipStream_t stream) {
    const float* scores  = (const float*)d_in[0];
    const int*   targets = (const int*)d_in[1];
    const int*   lengths = (const int*)d_in[2];
    float* ws = (float*)d_ws;

    crf_fwd_kernel<<<dim3(B_), dim3(256), 0, stream>>>(scores, targets, lengths, ws);
    reduce_kernel<<<dim3(1), dim3(64), 0, stream>>>(ws, (float*)d_out);
}

// Round 2
// 170.172 us; speedup vs baseline: 1.0242x; 1.0242x over previous
//
#include <hip/hip_runtime.h>
#include <hip/hip_bf16.h>
#include <stdint.h>

#define B_ 64
#define T_ 256
#define K_ 48
#define KK 2304               // K_*K_
#define D_PRE 6               // prefetch ring depth (slots); +1 dummy slot
#define START_TAG 46
#define END_TAG 47
// per tile: 9216 B split across 4 waves: each wave 2x dwordx4(1024B) + 1x dword(256B) = 3 instrs
// per-wave steady-state outstanding = 3*D_PRE = 18; wait immediate = 3*(D_PRE-1) = 15

typedef const __attribute__((address_space(1))) void* gas_t;
typedef __attribute__((address_space(3))) void* las_t;

__device__ __forceinline__ void issue_tile_w(const float* src, float* slot, int wid, int lane) {
    const float* s = src  + wid * 576;   // 576 floats = 2304 B per wave
    float*       d = slot + wid * 576;
    __builtin_amdgcn_global_load_lds((gas_t)(s + lane * 4),       (las_t)d,         16, 0, 0);
    __builtin_amdgcn_global_load_lds((gas_t)(s + 256 + lane * 4), (las_t)(d + 256), 16, 0, 0);
    __builtin_amdgcn_global_load_lds((gas_t)(s + 512 + lane),     (las_t)(d + 512),  4, 0, 0);
}

__launch_bounds__(256, 1)
__global__ void crf_fwd_kernel(const float* __restrict__ scores,
                               const int* __restrict__ targets,
                               const int* __restrict__ lengths,
                               float* __restrict__ ws) {
    __shared__ __align__(16) float tiles[(D_PRE + 1) * KK];  // +1 = dummy slot
    __shared__ float prev_s[K_];
    __shared__ float red_s[4];

    const int b    = blockIdx.x;
    const int tid  = threadIdx.x;
    const int lane = tid & 63;
    const int wid  = tid >> 6;

    int len = lengths[b];
    len = min(max(len, 1), T_);
    const int last_t = len - 1;  // tiles 1..last_t participate in the recurrence

    const float* sb = scores + (size_t)b * T_ * KK;

    // ---- gold score: one t per thread (T_ == blockDim) ----
    float g = 0.f;
    {
        const int t0 = tid;
        if (t0 < len) {
            const int tgt = targets[b * T_ + t0];
            g = sb[(size_t)t0 * KK + tgt];
        }
#pragma unroll
        for (int off = 1; off < 64; off <<= 1) g += __shfl_xor(g, off);
        if (lane == 0) red_s[wid] = g;
    }

    // ---- init: prev[j] = scores[b,0,START_TAG,j] ----
    if (tid < K_) prev_s[tid] = sb[START_TAG * K_ + tid];

    __syncthreads();  // drains all vm loads (gold gathers) -> clean vmcnt everywhere

    float gold_reg = 0.f;
    if (tid == 0) gold_reg = red_s[0] + red_s[1] + red_s[2] + red_s[3];

    // ---- prologue: all 4 waves fill the ring (dummy slot keeps counts uniform) ----
#pragma unroll
    for (int k = 1; k <= D_PRE; ++k) {
        const bool real = (k <= last_t);
        const float* src = real ? (sb + (size_t)k * KK) : sb;
        float* dst = real ? &tiles[(k % D_PRE) * KK] : &tiles[D_PRE * KK];
        issue_tile_w(src, dst, wid, lane);
    }

    // ---- main recurrence ----
    for (int t = 1; t <= last_t; ++t) {
        asm volatile("s_waitcnt vmcnt(15)" ::: "memory");   // this wave's tile-t loads landed
        asm volatile("s_waitcnt lgkmcnt(0)" ::: "memory");  // prev_s write done
        __builtin_amdgcn_s_barrier();  // A: tile t + prev visible to all

        float lse = 0.f;
        const float* tile = &tiles[(t % D_PRE) * KK];
        if (tid < 192) {
            const int j = tid >> 2, gq = tid & 3;
            float v[12];
            float m = -INFINITY;
#pragma unroll
            for (int it = 0; it < 12; ++it) {
                const int i = gq + (it << 2);          // 2-way LDS aliasing only
                const float x = tile[i * K_ + j] + prev_s[i];
                v[it] = x;
                m = fmaxf(m, x);
            }
            m = fmaxf(m, __shfl_xor(m, 1));
            m = fmaxf(m, __shfl_xor(m, 2));
            float s = 0.f;
#pragma unroll
            for (int it = 0; it < 12; ++it) s += __expf(v[it] - m);
            s += __shfl_xor(s, 1);
            s += __shfl_xor(s, 2);
            lse = m + __logf(s);
        }

        asm volatile("s_waitcnt lgkmcnt(0)" ::: "memory");  // all tile-t LDS reads retired
        __builtin_amdgcn_s_barrier();  // B: safe to overwrite slot / prev

        {
            const int tn = t + D_PRE;
            const bool real = (tn <= last_t);
            const float* src = real ? (sb + (size_t)tn * KK) : sb;
            float* dst = real ? &tiles[(tn % D_PRE) * KK] : &tiles[D_PRE * KK];
            issue_tile_w(src, dst, wid, lane);
        }
        if (tid < 192 && (tid & 3) == 0) prev_s[tid >> 2] = lse;
    }

    asm volatile("s_waitcnt vmcnt(0)" ::: "memory");   // drain dummies
    asm volatile("s_waitcnt lgkmcnt(0)" ::: "memory");
    __builtin_amdgcn_s_barrier();

    if (tid == 0) ws[b] = prev_s[END_TAG] - gold_reg;
}

__global__ void reduce_kernel(const float* __restrict__ ws, float* __restrict__ out) {
    float v = ws[threadIdx.x];
#pragma unroll
    for (int off = 1; off < 64; off <<= 1) v += __shfl_xor(v, off);
    if (threadIdx.x == 0) out[0] = v * (1.0f / 64.0f);
}

extern "C" void kernel_launch(void* const* d_in, const int* in_sizes, int n_in,
                              void* d_out, int out_size, void* d_ws, size_t ws_size,
                              hipStream_t stream) {
    const float* scores  = (const float*)d_in[0];
    const int*   targets = (const int*)d_in[1];
    const int*   lengths = (const int*)d_in[2];
    float* ws = (float*)d_ws;

    crf_fwd_kernel<<<dim3(B_), dim3(256), 0, stream>>>(scores, targets, lengths, ws);
    reduce_kernel<<<dim3(1), dim3(64), 0, stream>>>(ws, (float*)d_out);
}

// Round 4
// 124.041 us; speedup vs baseline: 1.4050x; 1.3719x over previous
//
#include <hip/hip_runtime.h>
#include <hip/hip_bf16.h>
#include <stdint.h>

#define B_ 64
#define T_ 256
#define K_ 48
#define KK 2304               // K_*K_
#define D_PRE 6               // ring slots; prefetch runs 5 ahead (+1 dummy slot)
#define START_TAG 46
#define END_TAG 47
#define LOG2E 1.4426950408889634f
#define LN2   0.6931471805599453f
// per tile: 9216 B split across 4 waves: each wave 2x dwordx4(1024B) + 1x dword(256B) = 3 instrs
// steady state per wave: 15 outstanding at iter entry, +3 issued, wait vmcnt(12) at iter end

typedef const __attribute__((address_space(1))) void* gas_t;
typedef __attribute__((address_space(3))) void* las_t;

#define EXP2F(x) __builtin_amdgcn_exp2f(x)   // v_exp_f32: 2^x
#define LOG2F(x) __builtin_amdgcn_logf(x)    // v_log_f32: log2(x)

__device__ __forceinline__ void issue_tile_w(const float* src, float* slot, int wid, int lane) {
    const float* s = src  + wid * 576;   // 576 floats = 2304 B per wave
    float*       d = slot + wid * 576;
    __builtin_amdgcn_global_load_lds((gas_t)(s + lane * 4),       (las_t)d,         16, 0, 0);
    __builtin_amdgcn_global_load_lds((gas_t)(s + 256 + lane * 4), (las_t)(d + 256), 16, 0, 0);
    __builtin_amdgcn_global_load_lds((gas_t)(s + 512 + lane),     (las_t)(d + 512),  4, 0, 0);
}

__device__ __forceinline__ float dpp_quad_add(float s) {
    float u = __int_as_float(__builtin_amdgcn_update_dpp(
        0, __float_as_int(s), 0xB1, 0xF, 0xF, true));   // quad_perm [1,0,3,2]
    s += u;
    u = __int_as_float(__builtin_amdgcn_update_dpp(
        0, __float_as_int(s), 0x4E, 0xF, 0xF, true));   // quad_perm [2,3,0,1]
    return s + u;
}

__launch_bounds__(256, 1)
__global__ void crf_fwd_kernel(const float* __restrict__ scores,
                               const int* __restrict__ targets,
                               const int* __restrict__ lengths,
                               float* __restrict__ ws) {
    __shared__ __align__(16) float tiles[(D_PRE + 1) * KK];  // 64512 B (+dummy)
    __shared__ float pbuf[2][K_];
    __shared__ float red_s[4];

    const int b    = blockIdx.x;
    const int tid  = threadIdx.x;
    const int lane = tid & 63;
    const int wid  = tid >> 6;

    int len = lengths[b];
    len = min(max(len, 1), T_);
    const int last_t = len - 1;  // tiles 1..last_t participate in the recurrence

    const float* sb = scores + (size_t)b * T_ * KK;

    // ---- gold score: one t per thread ----
    float g = 0.f;
    {
        if (tid < len) {
            const int tgt = targets[b * T_ + tid];
            g = sb[(size_t)tid * KK + tgt];
        }
#pragma unroll
        for (int off = 1; off < 64; off <<= 1) g += __shfl_xor(g, off);
        if (lane == 0) red_s[wid] = g;
    }

    // ---- init (log2 units): pbuf[1][j] = scores[b,0,START,j] * log2e ----
    if (tid < K_) pbuf[1][tid] = sb[START_TAG * K_ + tid] * LOG2E;

    // ---- prologue: all waves issue tiles 1..5 (dummies keep counts uniform) ----
#pragma unroll
    for (int k = 1; k <= D_PRE - 1; ++k) {
        const bool real = (k <= last_t);
        const float* src = real ? (sb + (size_t)k * KK) : sb;
        float* dst = real ? &tiles[(k % D_PRE) * KK] : &tiles[D_PRE * KK];
        issue_tile_w(src, dst, wid, lane);
    }
    asm volatile("s_waitcnt vmcnt(12)" ::: "memory");  // tile 1 landed
    __syncthreads();                                   // pbuf init + red_s visible

    float gold_reg = 0.f;
    if (tid == 0) gold_reg = red_s[0] + red_s[1] + red_s[2] + red_s[3];

    const int j  = tid >> 2;   // column, 0..47 (tid<192)
    const int gq = tid & 3;    // quad slot: rows gq, gq+4, ..., gq+44
    float accA = 0.f;          // sum of pbuf_t[0] over steps (valid on gq==0 lanes)

    // ---- main recurrence: ONE barrier per step ----
    for (int t = 1; t <= last_t; ++t) {
        {   // issue tile t+5 into slot (t+5)%D_PRE == (t-1)%D_PRE (reads retired last iter)
            const int tn = t + D_PRE - 1;
            const bool real = (tn <= last_t);
            const float* src = real ? (sb + (size_t)tn * KK) : sb;
            float* dst = real ? &tiles[(tn % D_PRE) * KK] : &tiles[D_PRE * KK];
            issue_tile_w(src, dst, wid, lane);
        }

        if (tid < 192) {
            const int rb = t & 1, wb = rb ^ 1;
            const float* tile = &tiles[(t % D_PRE) * KK];
            float p[12];
#pragma unroll
            for (int k = 0; k < 12; ++k) p[k] = pbuf[rb][gq + (k << 2)];
            accA += p[0];  // == pbuf_t[0] on gq==0 lanes
            float s0 = 0.f, s1 = 0.f, s2 = 0.f, s3 = 0.f;
#pragma unroll
            for (int k = 0; k < 12; k += 4) {
                s0 += EXP2F(fmaf(tile[(gq + (k << 2)) * K_ + j],       LOG2E, p[k]));
                s1 += EXP2F(fmaf(tile[(gq + ((k + 1) << 2)) * K_ + j], LOG2E, p[k + 1]));
                s2 += EXP2F(fmaf(tile[(gq + ((k + 2) << 2)) * K_ + j], LOG2E, p[k + 2]));
                s3 += EXP2F(fmaf(tile[(gq + ((k + 3) << 2)) * K_ + j], LOG2E, p[k + 3]));
            }
            float s = (s0 + s1) + (s2 + s3);
            s = dpp_quad_add(s);               // full-rate DPP quad reduction
            if (gq == 0) {
                // pbuf_{t+1}[j] = log2(s_j) - pbuf_t[0]  (shift keeps values bounded)
                pbuf[wb][j] = LOG2F(s) - p[0];
            }
        }

        asm volatile("s_waitcnt vmcnt(12)" ::: "memory");   // tile t+1 landed (this wave's part)
        asm volatile("s_waitcnt lgkmcnt(0)" ::: "memory");  // reads retired + pbuf write visible
        __builtin_amdgcn_s_barrier();
    }

    asm volatile("s_waitcnt vmcnt(0)" ::: "memory");   // drain dummies before exit
    asm volatile("s_waitcnt lgkmcnt(0)" ::: "memory");
    __builtin_amdgcn_s_barrier();

    if (tid == 0) {
        const float pEnd = pbuf[(last_t + 1) & 1][END_TAG];
        ws[b] = LN2 * (accA + pEnd) - gold_reg;
    }
}

__global__ void reduce_kernel(const float* __restrict__ ws, float* __restrict__ out) {
    float v = ws[threadIdx.x];
#pragma unroll
    for (int off = 1; off < 64; off <<= 1) v += __shfl_xor(v, off);
    if (threadIdx.x == 0) out[0] = v * (1.0f / 64.0f);
}

extern "C" void kernel_launch(void* const* d_in, const int* in_sizes, int n_in,
                              void* d_out, int out_size, void* d_ws, size_t ws_size,
                              hipStream_t stream) {
    const float* scores  = (const float*)d_in[0];
    const int*   targets = (const int*)d_in[1];
    const int*   lengths = (const int*)d_in[2];
    float* ws = (float*)d_ws;

    crf_fwd_kernel<<<dim3(B_), dim3(256), 0, stream>>>(scores, targets, lengths, ws);
    reduce_kernel<<<dim3(1), dim3(64), 0, stream>>>(ws, (float*)d_out);
}